// Round 7
// baseline (526.887 us; speedup 1.0000x reference)
//
#include <hip/hip_runtime.h>
#include <hip/hip_bf16.h>

#define BB 16
#define TT 16

typedef short short8  __attribute__((ext_vector_type(8)));
typedef short short4v __attribute__((ext_vector_type(4)));
typedef float f32x4   __attribute__((ext_vector_type(4)));

__device__ __forceinline__ ushort f2bf(float f) {
    uint u = __float_as_uint(f);
    u += 0x7FFFu + ((u >> 16) & 1u);      // RTNE
    return (ushort)(u >> 16);
}
__device__ __forceinline__ float bf2f(ushort h) { return __uint_as_float(((uint)h) << 16); }
__device__ __forceinline__ float fast_sigmoid(float x) { return 1.0f / (1.0f + __expf(-x)); }
__device__ __forceinline__ float fast_tanh(float x) {
    float e = __expf(2.0f * x);
    return 1.0f - 2.0f / (e + 1.0f);
}
__device__ __forceinline__ short8 pack8(const float4 a, const float4 b) {
    short8 r;
    r[0]=(short)f2bf(a.x); r[1]=(short)f2bf(a.y); r[2]=(short)f2bf(a.z); r[3]=(short)f2bf(a.w);
    r[4]=(short)f2bf(b.x); r[5]=(short)f2bf(b.y); r[6]=(short)f2bf(b.z); r[7]=(short)f2bf(b.w);
    return r;
}

// Pack fp32 weights src[CO][CINfull][NT] (tap-minor) slice ci_base..ci_base+KCp*32
// into bf16 MFMA A-fragments: frag fi=(tap*CBT+cb_base+cb)*KCp+kc, 64-lane contiguous.
__global__ __launch_bounds__(256)
void pack_frag(const float* __restrict__ src, ushort* __restrict__ dst,
               int CO, int CINfull, int ci_base, int KCp, int cb_base, int CBT, int NT) {
    int CBn = CO >> 4;
    int total = NT * CBn * KCp * 64;
    for (int i = blockIdx.x * 256 + threadIdx.x; i < total; i += gridDim.x * 256) {
        int lane = i & 63, rest = i >> 6;
        int kc = rest % KCp;
        int rest2 = rest / KCp;
        int cb = rest2 % CBn, tap = rest2 / CBn;
        int co = cb * 16 + (lane & 15);
        int ci0 = ci_base + kc * 32 + (lane >> 4) * 8;
        short8 v;
        #pragma unroll
        for (int e = 0; e < 8; ++e)
            v[e] = (short)f2bf(src[((size_t)co * CINfull + ci0 + e) * NT + tap]);
        size_t fi = ((size_t)(tap * CBT + cb_base + cb)) * KCp + kc;
        *(short8*)(dst + (fi * 64 + lane) * 8) = v;
    }
}

// Precompute Axc[bt][pix][192] = bf16( convX(x_t) + bias ):
//   co 0..127: gates-x conv + b_gates ; co 128..191: cand-x conv + b_can.
__global__ __launch_bounds__(512)
void conv_x192(const float* __restrict__ xall,   // [bt][64][1024] fp32 NCHW
               const ushort* __restrict__ wfX,   // frags [9][12cb][2kc]
               const float* __restrict__ b_gates,
               const float* __restrict__ b_can,
               ushort* __restrict__ axc)
{
    __shared__ ushort xb[4 * 34 * 64];           // rows R-1..R+2, swizzled chunks
    const int rt = blockIdx.x, bt = blockIdx.y;
    const int R  = rt * 2;
    const int tid = threadIdx.x;
    const float* xs = xall + (size_t)bt * 65536;

    for (int i = tid; i < 4 * 34 * 32; i += 512) {
        const int hp = i >> 5, cp = i & 31;
        const int tr = hp / 34, hc = hp - tr * 34;
        const int y = R - 1 + tr, x = hc - 1;
        uint val = 0;
        if ((unsigned)y < 32u && (unsigned)x < 32u) {
            const int pix = y * 32 + x;
            float v0 = xs[(size_t)(cp * 2) * 1024 + pix];
            float v1 = xs[(size_t)(cp * 2 + 1) * 1024 + pix];
            val = (uint)f2bf(v0) | ((uint)f2bf(v1) << 16);
        }
        const int c = cp >> 2;
        const int s = c ^ ((hc + 7) & 7);
        ((uint*)xb)[hp * 32 + (s << 2) + (cp & 3)] = val;
    }
    __syncthreads();

    const int w = tid >> 6, lane = tid & 63, lr = lane & 15, lg = lane >> 4;
    const int cb0 = (w & 3) * 3;     // 0,3,6,9
    const int pf0 = (w >> 2) * 2;    // 0,2

    f32x4 acc[3][2];
    #pragma unroll
    for (int i = 0; i < 3; ++i) { acc[i][0] = 0; acc[i][1] = 0; }

    #pragma unroll
    for (int tap = 0; tap < 9; ++tap) {
        const int ky = tap / 3, kx = tap - ky * 3;
        #pragma unroll
        for (int kc = 0; kc < 2; ++kc) {
            short8 a[3];
            #pragma unroll
            for (int i = 0; i < 3; ++i)
                a[i] = *(const short8*)(wfX + (size_t)(((tap * 12 + cb0 + i) * 2 + kc) * 512) + lane * 8);
            #pragma unroll
            for (int j = 0; j < 2; ++j) {
                const int px = (pf0 + j) * 16 + lr;
                const int tr = (px >> 5) + ky, hc = (px & 31) + kx;
                short8 bf = *(const short8*)(xb + (tr * 34 + hc) * 64 + (((kc * 4 + lg) ^ ((hc + 7) & 7)) << 3));
                #pragma unroll
                for (int i = 0; i < 3; ++i)
                    acc[i][j] = __builtin_amdgcn_mfma_f32_16x16x32_bf16(a[i], bf, acc[i][j], 0, 0, 0);
            }
        }
    }

    #pragma unroll
    for (int i = 0; i < 3; ++i) {
        const int co0 = (cb0 + i) * 16 + lg * 4;
        const float* bsrc = (co0 < 128) ? (b_gates + co0) : (b_can + co0 - 128);
        const f32x4 b4 = *(const f32x4*)bsrc;
        #pragma unroll
        for (int j = 0; j < 2; ++j) {
            const int px = (pf0 + j) * 16 + lr;
            const int y = R + (px >> 5), xx = px & 31;
            short4v s;
            #pragma unroll
            for (int r = 0; r < 4; ++r)
                s[r] = (short)f2bf(acc[i][j][r] + b4[r]);
            *(short4v*)(axc + ((size_t)bt * 1024 + y * 32 + xx) * 192 + co0) = s;
        }
    }
}

// ---- fused ConvGRU-ODE step (x-halves precomputed in axc) ----
// LDS (ushort idx): hbuf [0,17408) 8x34x128B ; obuf [17408,30464) 6x34x128B
//   overlay after A: rhbuf [0,8704) 4x34x128B ; ubuf f32 @byte 17408 (16KB)
//   hode f32 @byte 60928 (16KB).  Total 77312 B.
__global__ __launch_bounds__(512, 1)
void fused_step(const ushort* __restrict__ axc,
                const float* __restrict__ h_in,
                const ushort* __restrict__ h_inb,
                float* __restrict__ h_out,
                ushort* __restrict__ h_outb,
                const ushort* __restrict__ wfO,
                const ushort* __restrict__ wfGh,
                const ushort* __restrict__ wfCh,
                const float* __restrict__ b_ode,
                const float* __restrict__ tsteps,
                const float* __restrict__ mask,
                int t)
{
    extern __shared__ ushort smem[];
    float*  smemf = (float*)smem;
    ushort* hbuf  = smem;
    ushort* obuf  = smem + 17408;
    ushort* rhbuf = smem;
    float*  ubuf  = smemf + 4352;
    float*  hode  = smemf + 15232;

    const int rt = blockIdx.x, b = blockIdx.y;
    const int R  = rt * 2;
    const int tid = threadIdx.x;
    const int w = tid >> 6, lane = tid & 63, lr = lane & 15, lg = lane >> 4;
    const int bti = b * TT + (TT - 1 - t);

    const ushort* hbb = h_inb + (size_t)b * 1026 * 64;
    const float*  hb  = h_in  + (size_t)b * 65536;
    const ushort* axb = axc + (size_t)bti * 1024 * 192;

    // ---- stage: hbuf rows R-3..R+4 ; obuf halo cols + OOB rows zero ----
    for (int i = tid; i < 2176; i += 512) {
        const int tr = i / 272, rem = i - tr * 272;
        const int hc = rem >> 3;
        const int y  = R - 3 + tr;
        short8 v = (short8)0;
        if ((unsigned)y < 32u && hc != 0 && hc != 33)
            v = *(const short8*)(hbb + ((size_t)(y * 32 + hc)) * 64 + (rem & 7) * 8);
        *(short8*)(hbuf + (size_t)i * 8) = v;
    }
    for (int i = tid; i < 1632; i += 512) {
        const int tr = i / 272, rem = i - tr * 272;
        const int hc = rem >> 3;
        const int y  = R - 2 + tr;
        if (hc == 0 || hc == 33 || (unsigned)y >= 32u)
            *(short8*)(obuf + (size_t)i * 8) = (short8)0;
    }
    __syncthreads();

    // ---- phase A: h_ode rows R-2..R+3 (K=64 over hbuf) ----
    {
        const int cb0 = (w & 1) * 2;
        const int pxg = w >> 1;
        f32x4 accA[2][3];
        #pragma unroll
        for (int i = 0; i < 2; ++i)
            #pragma unroll
            for (int j = 0; j < 3; ++j) accA[i][j] = 0;

        #pragma unroll
        for (int tap = 0; tap < 9; ++tap) {
            const int ky = tap / 3, kx = tap - ky * 3;
            #pragma unroll
            for (int kc = 0; kc < 2; ++kc) {
                short8 a0 = *(const short8*)(wfO + (size_t)(((tap * 4 + cb0 + 0) * 2 + kc) * 512) + lane * 8);
                short8 a1 = *(const short8*)(wfO + (size_t)(((tap * 4 + cb0 + 1) * 2 + kc) * 512) + lane * 8);
                #pragma unroll
                for (int j = 0; j < 3; ++j) {
                    const int p  = (3 * pxg + j) * 16 + lr;
                    const int tr = (p >> 5) + ky, hc = (p & 31) + kx;
                    short8 bf = *(const short8*)(hbuf + (tr * 34 + hc) * 64 + ((((kc << 2) + lg) ^ ((hc + 7) & 7)) << 3));
                    accA[0][j] = __builtin_amdgcn_mfma_f32_16x16x32_bf16(a0, bf, accA[0][j], 0, 0, 0);
                    accA[1][j] = __builtin_amdgcn_mfma_f32_16x16x32_bf16(a1, bf, accA[1][j], 0, 0, 0);
                }
            }
        }
        const float dt = (t == 0) ? -0.01f : (tsteps[TT - 1 - t] - tsteps[TT - t]);
        #pragma unroll
        for (int i = 0; i < 2; ++i) {
            #pragma unroll
            for (int j = 0; j < 3; ++j) {
                const int co0 = (cb0 + i) * 16 + lg * 4;
                const int p = (3 * pxg + j) * 16 + lr;
                const int orow = p >> 5, c = p & 31;
                const int y = R - 2 + orow;
                if ((unsigned)y < 32u) {
                    const f32x4 h4 = *(const f32x4*)(hb + ((size_t)(y * 32 + c)) * 64 + co0);
                    const f32x4 b4 = *(const f32x4*)(b_ode + co0);
                    f32x4 ho;
                    #pragma unroll
                    for (int r = 0; r < 4; ++r)
                        ho[r] = h4[r] + fast_tanh(accA[i][j][r] + b4[r]) * dt;
                    short4v s;
                    #pragma unroll
                    for (int r = 0; r < 4; ++r) s[r] = (short)f2bf(ho[r]);
                    *(short4v*)(obuf + (orow * 34 + c + 1) * 64 + (((co0 >> 3) ^ (c & 7)) << 3) + (co0 & 7)) = s;
                    if ((unsigned)(y - R) < 2u)
                        *(f32x4*)(hode + ((y - R) * 32 + c) * 64 + (((co0 >> 2) ^ (c & 15)) << 2)) = ho;
                }
            }
        }
    }
    __syncthreads();

    // rhbuf: zero halo cols + OOB rows (overlays dead hbuf)
    for (int i = tid; i < 1088; i += 512) {
        const int tr = i / 272, rem = i - tr * 272;
        const int hc = rem >> 3;
        const int y  = R - 1 + tr;
        if (hc == 0 || hc == 33 || (unsigned)y >= 32u)
            *(short8*)(rhbuf + (size_t)i * 8) = (short8)0;
    }

    // ---- phase B: gates rows R-1..R+2 (K=64 over obuf, acc init from Gx) ----
    {
        const int cq = w & 3, ph = w >> 2;
        f32x4 accB[2][4];
        #pragma unroll
        for (int i = 0; i < 2; ++i) {
            const int cog0 = (2 * cq + i) * 16 + lg * 4;
            #pragma unroll
            for (int j = 0; j < 4; ++j) {
                const int f = 4 * ph + j;
                const int y = R - 1 + (f >> 1);
                const int c = (f & 1) * 16 + lr;
                f32x4 g = {0.f, 0.f, 0.f, 0.f};
                if ((unsigned)y < 32u) {
                    short4v gx = *(const short4v*)(axb + ((size_t)(y * 32 + c)) * 192 + cog0);
                    #pragma unroll
                    for (int r = 0; r < 4; ++r) g[r] = bf2f((ushort)gx[r]);
                }
                accB[i][j] = g;
            }
        }

        #pragma unroll
        for (int tap = 0; tap < 9; ++tap) {
            const int ky = tap / 3, kx = tap - ky * 3;
            #pragma unroll
            for (int kc = 0; kc < 2; ++kc) {
                short8 a0 = *(const short8*)(wfGh + (size_t)(((tap * 8 + 2 * cq + 0) * 2 + kc) * 512) + lane * 8);
                short8 a1 = *(const short8*)(wfGh + (size_t)(((tap * 8 + 2 * cq + 1) * 2 + kc) * 512) + lane * 8);
                #pragma unroll
                for (int j = 0; j < 4; ++j) {
                    const int f  = 4 * ph + j;
                    const int tr = (f >> 1) + ky;
                    const int hc = (f & 1) * 16 + lr + kx;
                    short8 bf = *(const short8*)(obuf + (tr * 34 + hc) * 64 + ((((kc << 2) + lg) ^ ((hc + 7) & 7)) << 3));
                    accB[0][j] = __builtin_amdgcn_mfma_f32_16x16x32_bf16(a0, bf, accB[0][j], 0, 0, 0);
                    accB[1][j] = __builtin_amdgcn_mfma_f32_16x16x32_bf16(a1, bf, accB[1][j], 0, 0, 0);
                }
            }
        }
        #pragma unroll
        for (int i = 0; i < 2; ++i) {
            const int cog = (2 * cq + i) * 16 + lg * 4;
            #pragma unroll
            for (int j = 0; j < 4; ++j) {
                const int f = 4 * ph + j;
                const int y = R - 1 + (f >> 1);
                const int c = (f & 1) * 16 + lr;
                if (cq < 2) {   // reset -> rh = sigmoid(r)*h_ode
                    if ((unsigned)y < 32u) {
                        const int tro = (f >> 1) + 1;
                        const int key = (((cog >> 3) ^ (c & 7)) << 3) + (cog & 7);
                        short4v ho4 = *(const short4v*)(obuf + (tro * 34 + c + 1) * 64 + key);
                        short4v s;
                        #pragma unroll
                        for (int r = 0; r < 4; ++r)
                            s[r] = (short)f2bf(fast_sigmoid(accB[i][j][r]) * bf2f((ushort)ho4[r]));
                        *(short4v*)(rhbuf + ((f >> 1) * 34 + c + 1) * 64 + key) = s;
                    }
                } else if ((unsigned)(y - R) < 2u) {   // update gate u (central rows)
                    const int cu = cog - 64;
                    f32x4 u;
                    #pragma unroll
                    for (int r = 0; r < 4; ++r)
                        u[r] = fast_sigmoid(accB[i][j][r]);
                    *(f32x4*)(ubuf + ((y - R) * 32 + c) * 64 + (((cu >> 2) ^ (c & 15)) << 2)) = u;
                }
            }
        }
    }
    __syncthreads();

    // ---- phase C: cand rows R..R+1 (K=64 over rhbuf, acc init from Cx) ; GRU update ----
    {
        const int cf = w & 3, ph2 = w >> 2;
        const int co0 = cf * 16 + lg * 4;
        f32x4 accC[2];
        #pragma unroll
        for (int j = 0; j < 2; ++j) {
            const int c = j * 16 + lr;
            const int pix = (R + ph2) * 32 + c;
            short4v cx = *(const short4v*)(axb + (size_t)pix * 192 + 128 + co0);
            f32x4 g;
            #pragma unroll
            for (int r = 0; r < 4; ++r) g[r] = bf2f((ushort)cx[r]);
            accC[j] = g;
        }

        #pragma unroll
        for (int tap = 0; tap < 9; ++tap) {
            const int ky = tap / 3, kx = tap - ky * 3;
            #pragma unroll
            for (int kc = 0; kc < 2; ++kc) {
                short8 a = *(const short8*)(wfCh + (size_t)(((tap * 4 + cf) * 2 + kc) * 512) + lane * 8);
                #pragma unroll
                for (int j = 0; j < 2; ++j) {
                    const int tr = ph2 + ky;
                    const int hc = j * 16 + lr + kx;
                    short8 bf = *(const short8*)(rhbuf + (tr * 34 + hc) * 64 + ((((kc << 2) + lg) ^ ((hc + 7) & 7)) << 3));
                    accC[j] = __builtin_amdgcn_mfma_f32_16x16x32_bf16(a, bf, accC[j], 0, 0, 0);
                }
            }
        }
        const float m = mask[b * TT + (TT - 1 - t)];
        const int y = R + ph2;
        #pragma unroll
        for (int j = 0; j < 2; ++j) {
            const int c = j * 16 + lr;
            const int pi = ph2 * 32 + c;
            const int sw = ((co0 >> 2) ^ (c & 15)) << 2;
            const f32x4 ho = *(const f32x4*)(hode + pi * 64 + sw);
            const f32x4 u  = *(const f32x4*)(ubuf + pi * 64 + sw);
            f32x4 o;
            short4v s;
            #pragma unroll
            for (int r = 0; r < 4; ++r) {
                const float cand = fast_tanh(accC[j][r]);
                o[r] = ho[r] + m * u[r] * (cand - ho[r]);
                s[r] = (short)f2bf(o[r]);
            }
            const int pix = y * 32 + c;
            *(f32x4*)(h_out + (size_t)b * 65536 + (size_t)pix * 64 + co0) = o;
            *(short4v*)(h_outb + ((size_t)b * 1026 + 1 + pix) * 64
                        + (((co0 >> 3) ^ (c & 7)) << 3) + (co0 & 7)) = s;
        }
    }
}

// Head: z = relu(W1 h + b1); z2 = W2 z + b2; out NCHW (mean, |std|)
__global__ __launch_bounds__(256)
void head_mfma(const float* __restrict__ h,
               const ushort* __restrict__ w1f, const float* __restrict__ b1,
               const ushort* __restrict__ w2f, const float* __restrict__ b2,
               float* __restrict__ outp)
{
    __shared__ ushort hlds[64 * 64];
    __shared__ ushort zlds[64 * 64];
    const int blk = blockIdx.x, b = blk >> 4, pixb = (blk & 15) * 64;
    const int tid = threadIdx.x, wv = tid >> 6, lane = tid & 63, lr = lane & 15, lg = lane >> 4;
    const float* hb = h + ((size_t)b * 1024 + pixb) * 64;

    for (int idx = tid; idx < 64 * 8; idx += 256) {
        const int c = idx & 7, px = idx >> 3;
        const float4* p = (const float4*)(hb + (size_t)px * 64 + c * 8);
        *(short8*)(hlds + px * 64 + ((c ^ (px & 7)) << 3)) = pack8(p[0], p[1]);
    }
    __syncthreads();

    f32x4 acc1[4]; acc1[0]=0; acc1[1]=0; acc1[2]=0; acc1[3]=0;
    #pragma unroll
    for (int kc = 0; kc < 2; ++kc) {
        short8 a = *(const short8*)(w1f + (((size_t)wv * 2 + kc) * 64 + lane) * 8);
        #pragma unroll
        for (int p = 0; p < 4; ++p) {
            const int hp = p * 16 + lr;
            short8 bf = *(const short8*)(hlds + hp * 64 + (((kc * 4 + lg) ^ (hp & 7)) << 3));
            acc1[p] = __builtin_amdgcn_mfma_f32_16x16x32_bf16(a, bf, acc1[p], 0, 0, 0);
        }
    }
    {
        const int co0 = wv * 16 + lg * 4;
        const f32x4 b4 = *(const f32x4*)(b1 + co0);
        #pragma unroll
        for (int p = 0; p < 4; ++p) {
            const int px = p * 16 + lr;
            short4v s;
            #pragma unroll
            for (int r = 0; r < 4; ++r)
                s[r] = (short)f2bf(fmaxf(acc1[p][r] + b4[r], 0.0f));
            *(short4v*)(zlds + px * 64 + (((co0 >> 3) ^ (px & 7)) << 3) + (co0 & 7)) = s;
        }
    }
    __syncthreads();

    f32x4 acc2[2][4];
    #pragma unroll
    for (int gi = 0; gi < 2; ++gi)
        #pragma unroll
        for (int p = 0; p < 4; ++p) acc2[gi][p] = 0;
    #pragma unroll
    for (int kc = 0; kc < 2; ++kc) {
        short8 a0 = *(const short8*)(w2f + ((((size_t)wv * 2 + 0) * 2 + kc) * 64 + lane) * 8);
        short8 a1 = *(const short8*)(w2f + ((((size_t)wv * 2 + 1) * 2 + kc) * 64 + lane) * 8);
        #pragma unroll
        for (int p = 0; p < 4; ++p) {
            const int hp = p * 16 + lr;
            short8 bf = *(const short8*)(zlds + hp * 64 + (((kc * 4 + lg) ^ (hp & 7)) << 3));
            acc2[0][p] = __builtin_amdgcn_mfma_f32_16x16x32_bf16(a0, bf, acc2[0][p], 0, 0, 0);
            acc2[1][p] = __builtin_amdgcn_mfma_f32_16x16x32_bf16(a1, bf, acc2[1][p], 0, 0, 0);
        }
    }
    #pragma unroll
    for (int gi = 0; gi < 2; ++gi) {
        const int co0 = wv * 32 + gi * 16 + lg * 4;
        const f32x4 b4 = *(const f32x4*)(b2 + co0);
        #pragma unroll
        for (int p = 0; p < 4; ++p) {
            const int px = pixb + p * 16 + lr;
            #pragma unroll
            for (int r = 0; r < 4; ++r) {
                const int co = co0 + r;
                const float v = acc2[gi][p][r] + b4[r];
                if (co < 64)
                    outp[((size_t)b * 64 + co) * 1024 + px] = v;
                else
                    outp[(size_t)BB * 64 * 1024 + ((size_t)b * 64 + (co - 64)) * 1024 + px] = fabsf(v);
            }
        }
    }
}

extern "C" void kernel_launch(void* const* d_in, const int* in_sizes, int n_in,
                              void* d_out, int out_size, void* d_ws, size_t ws_size,
                              hipStream_t stream)
{
    const float* xall    = (const float*)d_in[0];
    const float* tsteps  = (const float*)d_in[1];
    const float* mask    = (const float*)d_in[2];
    const float* w_gates = (const float*)d_in[3];
    const float* b_gates = (const float*)d_in[4];
    const float* w_can   = (const float*)d_in[5];
    const float* b_can   = (const float*)d_in[6];
    const float* w_ode   = (const float*)d_in[7];
    const float* b_ode   = (const float*)d_in[8];
    const float* w_t1    = (const float*)d_in[9];
    const float* b_t1    = (const float*)d_in[10];
    const float* w_t2    = (const float*)d_in[11];
    const float* b_t2    = (const float*)d_in[12];
    float* out = (float*)d_out;

    // ws: h0,h1 fp32 (4MB ea) | h0b,h1b bf16-swz (2.1MB ea) | Axc bf16 (100.7MB) | weight frags
    float*  h0   = (float*)d_ws;
    float*  h1   = h0 + (size_t)BB * 65536;
    ushort* h0b  = (ushort*)(h1 + (size_t)BB * 65536);
    ushort* h1b  = h0b + (size_t)BB * 1026 * 64;
    ushort* axc  = h1b + (size_t)BB * 1026 * 64;
    ushort* wfX  = axc + (size_t)256 * 1024 * 192;
    ushort* wfGh = wfX  + (size_t)216 * 512;
    ushort* wfCh = wfGh + (size_t)144 * 512;
    ushort* wfO  = wfCh + (size_t)72 * 512;
    ushort* wf1  = wfO  + (size_t)72 * 512;
    ushort* wf2  = wf1  + (size_t)8 * 512;

    hipMemsetAsync(h0, 0, (size_t)BB * 65536 * sizeof(float), stream);
    hipMemsetAsync(h0b, 0, (size_t)BB * 1026 * 64 * 2 * sizeof(ushort), stream);

    // weight fragment packing
    pack_frag<<<dim3(36), 256, 0, stream>>>(w_gates, wfX,  128, 128, 0,  2, 0, 12, 9);
    pack_frag<<<dim3(18), 256, 0, stream>>>(w_can,   wfX,  64,  128, 0,  2, 8, 12, 9);
    pack_frag<<<dim3(36), 256, 0, stream>>>(w_gates, wfGh, 128, 128, 64, 2, 0, 8,  9);
    pack_frag<<<dim3(18), 256, 0, stream>>>(w_can,   wfCh, 64,  128, 64, 2, 0, 4,  9);
    pack_frag<<<dim3(18), 256, 0, stream>>>(w_ode,   wfO,  64,  64,  0,  2, 0, 4,  9);
    pack_frag<<<dim3(2),  256, 0, stream>>>(w_t1,    wf1,  64,  64,  0,  2, 0, 4,  1);
    pack_frag<<<dim3(4),  256, 0, stream>>>(w_t2,    wf2,  128, 64,  0,  2, 0, 8,  1);

    // precompute x-convs (+biases) for all (b,t)
    conv_x192<<<dim3(16, 256), 512, 0, stream>>>(xall, wfX, b_gates, b_can, axc);

    hipFuncSetAttribute(reinterpret_cast<const void*>(fused_step),
                        hipFuncAttributeMaxDynamicSharedMemorySize, 77312);

    for (int t = 0; t < TT; ++t) {
        const float*  hin   = (t & 1) ? h1  : h0;
        float*        hout  = (t & 1) ? h0  : h1;
        const ushort* hinb  = (t & 1) ? h1b : h0b;
        ushort*       houtb = (t & 1) ? h0b : h1b;
        fused_step<<<dim3(16, BB), 512, 77312, stream>>>(axc, hin, hinb, hout, houtb,
                                                         wfO, wfGh, wfCh,
                                                         b_ode, tsteps, mask, t);
    }
    head_mfma<<<dim3(256), 256, 0, stream>>>(h0, wf1, b_t1, wf2, b_t2, out);
}